// Round 6
// baseline (823.898 us; speedup 1.0000x reference)
//
#include <hip/hip_runtime.h>
#include <hip/hip_bf16.h>
#include <cstdint>

// ---- problem constants (bs=4, slen=1024 -> T=4096; dim=2048; hidden=1024; E=8; top-2) ----
#define TTOK   4096
#define DIM    2048
#define HID    1024
#define NEXP   8          // routed experts
#define GROWS  12288      // TTOK*2 routed rows + TTOK shared rows

typedef __attribute__((ext_vector_type(8))) __bf16 bf16x8;
typedef __attribute__((ext_vector_type(4))) float  f32x4;

__device__ __forceinline__ void glds16(const void* g, void* l) {
  __builtin_amdgcn_global_load_lds((const __attribute__((address_space(1))) void*)g,
                                   (__attribute__((address_space(3))) void*)l,
                                   16, 0, 0);
}

// ---------------- weight conversion (standalone again, for top-5 visibility) ----------------
// w13cat (9 x 2048 x 2048): rows INTERLEAVED per expert: new_r = 2j -> w1[j], 2j+1 -> w3[j],
// so GEMM1 output col pairs (2j,2j+1) = (h1_j,h3_j) -> silu fused in GEMM1 epilogue via shfl_xor(1).
// w2cat (9 x 2048 x 1024) plain bf16 cast.
__global__ void convert_w(const float* __restrict__ w1, const float* __restrict__ w2,
                          const float* __restrict__ w3, const float* __restrict__ ws1,
                          const float* __restrict__ ws2, const float* __restrict__ ws3,
                          __bf16* __restrict__ w13, __bf16* __restrict__ w2c) {
  const int N1 = 9 * 2048 * 2048 / 8;   // 16B-out chunks for w13
  const int N2 = 9 * 2048 * 1024 / 8;   // chunks for w2c
  int s = blockIdx.x * 256 + threadIdx.x;
  const float* src;
  __bf16* dst;
  if (s < N1) {
    int e  = s / 524288;            // 2048*2048/8
    int r  = (s % 524288) / 256;    // source row 0..2047
    int c  = (s % 256) * 8;
    int nr;
    if (r < 1024) { src = (e < 8 ? w1 + ((size_t)e * 1024 + r) * 2048 : ws1 + (size_t)r * 2048) + c;
                    nr = 2 * r; }
    else          { src = (e < 8 ? w3 + ((size_t)e * 1024 + (r - 1024)) * 2048 : ws3 + (size_t)(r - 1024) * 2048) + c;
                    nr = 2 * (r - 1024) + 1; }
    dst = w13 + ((size_t)e * 2048 + nr) * 2048 + c;
  } else {
    int s2 = s - N1;
    if (s2 >= N2) return;
    int e  = s2 / 262144;           // 2048*1024/8
    int r  = (s2 % 262144) / 128;   // row (d) 0..2047
    int c  = (s2 % 128) * 8;
    src = (e < 8 ? w2 + ((size_t)e * 2048 + r) * 1024 : ws2 + (size_t)r * 1024) + c;
    dst = w2c + ((size_t)e * 2048 + r) * 1024 + c;
  }
  float4 a = *(const float4*)(src);
  float4 b = *(const float4*)(src + 4);
  bf16x8 o;
  o[0]=(__bf16)a.x; o[1]=(__bf16)a.y; o[2]=(__bf16)a.z; o[3]=(__bf16)a.w;
  o[4]=(__bf16)b.x; o[5]=(__bf16)b.y; o[6]=(__bf16)b.z; o[7]=(__bf16)b.w;
  *(bf16x8*)dst = o;
}

// ---------------- router + FUSED scan (last block computes offs) ----------------
__global__ void router_k(const float* __restrict__ x, const float* __restrict__ gw,
                         int* __restrict__ sel, float* __restrict__ sco,
                         int* __restrict__ counts, int* __restrict__ done,
                         int* __restrict__ offs) {
  int t    = blockIdx.x * 4 + (threadIdx.x >> 6);
  int lane = threadIdx.x & 63;
  const float* xr = x + (size_t)t * DIM;
  float acc[NEXP];
  #pragma unroll
  for (int e = 0; e < NEXP; ++e) acc[e] = 0.f;
  for (int d = lane * 4; d < DIM; d += 256) {
    float4 xv = *(const float4*)(xr + d);
    #pragma unroll
    for (int e = 0; e < NEXP; ++e) {
      float4 gv = *(const float4*)(gw + (size_t)e * DIM + d);
      acc[e] += xv.x * gv.x + xv.y * gv.y + xv.z * gv.z + xv.w * gv.w;
    }
  }
  #pragma unroll
  for (int off = 32; off; off >>= 1)
    #pragma unroll
    for (int e = 0; e < NEXP; ++e) acc[e] += __shfl_xor(acc[e], off);
  if (lane == 0) {
    float s[NEXP];
    #pragma unroll
    for (int e = 0; e < NEXP; ++e) s[e] = 1.f / (1.f + expf(-acc[e]));
    int e0 = 0;
    #pragma unroll
    for (int e = 1; e < NEXP; ++e) if (s[e] > s[e0]) e0 = e;
    int e1 = (e0 == 0) ? 1 : 0;
    #pragma unroll
    for (int e = 0; e < NEXP; ++e) if (e != e0 && s[e] > s[e1]) e1 = e;
    sel[2 * t] = e0; sel[2 * t + 1] = e1;
    sco[2 * t] = s[e0]; sco[2 * t + 1] = s[e1];
    atomicAdd(&counts[e0], 1); atomicAdd(&counts[e1], 1);
  }
  // fused exclusive scan: the LAST block to finish computes offs.
  __syncthreads();  // implies vmcnt drain: this block's counts-atomics completed
  if (threadIdx.x == 0) {
    __threadfence();
    int old = atomicAdd(done, 1);
    if (old == gridDim.x - 1) {
      int o = 0;
      #pragma unroll
      for (int e = 0; e < NEXP; ++e) {
        int c = atomicAdd(&counts[e], 0);   // L2-coherent read
        offs[e] = o; o += c;
      }
      offs[NEXP] = o;            // == 8192
      offs[NEXP + 1] = o + TTOK; // == 12288
    }
  }
}

// ---------------- gather: write score-scaled bf16 rows into compact segments ----------------
__global__ void gather_k(const float* __restrict__ x, const int* __restrict__ sel,
                         const float* __restrict__ sco, const int* __restrict__ offs,
                         int* __restrict__ cursor, int* __restrict__ token_rows,
                         __bf16* __restrict__ xg) {
  __shared__ int   rows[3];
  __shared__ float ss[3];
  int t = blockIdx.x;
  if (threadIdx.x == 0) {
    int e0 = sel[2 * t], e1 = sel[2 * t + 1];
    int r0 = offs[e0] + atomicAdd(&cursor[e0], 1);
    int r1 = offs[e1] + atomicAdd(&cursor[e1], 1);
    int r2 = 8192 + t; // shared segment starts at 8192 always
    rows[0] = r0; rows[1] = r1; rows[2] = r2;
    ss[0] = sco[2 * t]; ss[1] = sco[2 * t + 1]; ss[2] = 1.0f;
    token_rows[3 * t] = r0; token_rows[3 * t + 1] = r1; token_rows[3 * t + 2] = r2;
  }
  __syncthreads();
  int c = threadIdx.x * 8;
  float4 v0 = *(const float4*)(x + (size_t)t * DIM + c);
  float4 v1 = *(const float4*)(x + (size_t)t * DIM + c + 4);
  #pragma unroll
  for (int j = 0; j < 3; ++j) {
    float s = ss[j];
    bf16x8 o;
    o[0]=(__bf16)(v0.x*s); o[1]=(__bf16)(v0.y*s); o[2]=(__bf16)(v0.z*s); o[3]=(__bf16)(v0.w*s);
    o[4]=(__bf16)(v1.x*s); o[5]=(__bf16)(v1.y*s); o[6]=(__bf16)(v1.z*s); o[7]=(__bf16)(v1.w*s);
    *(bf16x8*)(xg + (size_t)rows[j] * DIM + c) = o;
  }
}

// ---------------- GEMM1: 128x128 tile, BK=64, TWO waves, per-wave 64x128 acc ----------------
// LDS-throughput fix: reads/MFMA drops 0.5 -> 0.375 (per K-step per wave: 8 A + 16 B
// ds_read_b128 feeding 64 MFMA) vs the 4-wave 64x64 layout (16 reads / 32 MFMA). The LDS
// unit was the saturated pipe (per-CU ~1540cy LDS vs ~320cy MFMA) -> MfmaUtil capped at 22%.
// SINGLE-buffered 32 KB LDS -> ~4 blocks/CU; the per-kstep staging drain is hidden by
// co-resident blocks (m114/m97 mechanism, proven at 874 TF dense).
// LDS: chunk j (16B) of tile-row r stored at slot j^(r&7); staging permutes the GLOBAL chunk
// per lane (glds16 LDS dest is base+lane*16, fixed — m104). Same verified swizzle/fragment
// formulas as prior rounds (0 bank conflicts measured).
// Fused silu epilogue (w13 rows interleaved): col pairs (2j,2j+1)=(h1_j,h3_j) via shfl_xor(1).
__launch_bounds__(128)
__global__ void gemm_wide(const __bf16* __restrict__ A, const __bf16* __restrict__ Bw,
                          __bf16* __restrict__ Hb, const int* __restrict__ offs,
                          int K_, int N_) {
  int z  = blockIdx.z;
  int o0 = offs[z];
  int ne = offs[z + 1] - o0;

  int flat = blockIdx.y * 32 + blockIdx.x;       // 0..511, ascending in dispatch order
  int nid  = (flat & 7) * 64 + (flat >> 3);      // bijective XCD chunking (512 % 8 == 0)
  int bm   = nid & 31;
  int bn   = nid >> 5;

  if (bm * 128 >= ne) return;

  const __bf16* Aseg = A  + (size_t)(o0 + bm * 128) * K_;
  const __bf16* Bseg = Bw + ((size_t)z * N_ + bn * 128) * K_;

  __shared__ __align__(16) __bf16 sA[128 * 64];
  __shared__ __align__(16) __bf16 sB[128 * 64];

  int tid  = threadIdx.x;
  int wave = tid >> 6, lane = tid & 63;
  int fr = lane & 15;   // fragment row (m for A, n for B, also out col)
  int fq = lane >> 4;   // quad
  int sw = fr & 7;      // lane-constant XOR swizzle (row strides are mult of 8)

  // staging bases: rA0 = tid>>3 (row 0..15), ch = tid&7 (chunk); c8 = ch ^ (rA0&7).
  // row(it) = it*16 + rA0 and 16 == 0 (mod 8) -> swizzle term it-invariant.
  int rA0 = tid >> 3;
  int c8  = (tid & 7) ^ (rA0 & 7);
  const __bf16* aP = Aseg + (size_t)rA0 * K_ + c8 * 8;
  const __bf16* bP = Bseg + (size_t)rA0 * K_ + c8 * 8;

  f32x4 acc[4][8];
  #pragma unroll
  for (int i = 0; i < 4; ++i)
    #pragma unroll
    for (int j = 0; j < 8; ++j) acc[i][j] = (f32x4){0.f, 0.f, 0.f, 0.f};

  const int nk = K_ >> 6;
  for (int t = 0; t < nk; ++t) {
    int k0 = t << 6;
    #pragma unroll
    for (int it = 0; it < 8; ++it) {
      glds16(aP + k0 + (size_t)it * 16 * K_, &sA[(it * 128 + tid) * 8]);
      glds16(bP + k0 + (size_t)it * 16 * K_, &sB[(it * 128 + tid) * 8]);
    }
    __syncthreads();   // drain; hidden by ~4 co-resident blocks
    #pragma unroll
    for (int kk = 0; kk < 2; ++kk) {
      int slot = ((kk * 4 + fq) ^ sw) * 8;
      bf16x8 af[4], bb[8];
      #pragma unroll
      for (int i = 0; i < 4; ++i)
        af[i] = *(const bf16x8*)(sA + (wave * 64 + i * 16 + fr) * 64 + slot);
      #pragma unroll
      for (int j = 0; j < 8; ++j)
        bb[j] = *(const bf16x8*)(sB + (j * 16 + fr) * 64 + slot);
      #pragma unroll
      for (int i = 0; i < 4; ++i)
        #pragma unroll
        for (int j = 0; j < 8; ++j)
          acc[i][j] = __builtin_amdgcn_mfma_f32_16x16x32_bf16(af[i], bb[j], acc[i][j], 0, 0, 0);
    }
    __syncthreads();   // reads done before next stage overwrites
  }

  // epilogue: C/D layout col = lane&15 (=fr), row = fq*4 + r   [m89/m91 verified]
  #pragma unroll
  for (int mi = 0; mi < 4; ++mi) {
    #pragma unroll
    for (int r = 0; r < 4; ++r) {
      int rl = bm * 128 + wave * 64 + mi * 16 + fq * 4 + r;
      bool ok = rl < ne;
      int grow = o0 + rl;
      #pragma unroll
      for (int ni = 0; ni < 8; ++ni) {
        float v = acc[mi][ni][r];
        float o = __shfl_xor(v, 1);          // partner holds the other half of (h1,h3) pair
        float h1 = (fr & 1) ? o : v;
        float h3 = (fr & 1) ? v : o;
        float g  = h1 / (1.f + expf(-h1)) * h3;
        if (ok && !(fr & 1)) {
          int hcol = bn * 64 + ni * 8 + (fr >> 1);
          Hb[(size_t)grow * 1024 + hcol] = (__bf16)g;
        }
      }
    }
  }
}

// ---------------- GEMM2: proven R5 loop (4 LDS objects, counted vmcnt), c2 fp32 stores ----------------
#define BAR() do { asm volatile("" ::: "memory"); __builtin_amdgcn_s_barrier(); \
                   asm volatile("" ::: "memory"); } while (0)

__launch_bounds__(256)
__global__ void gemm_nt2(const __bf16* __restrict__ A, const __bf16* __restrict__ Bw,
                         float* __restrict__ c2a, float* __restrict__ c2b,
                         const int* __restrict__ offs, int K_, int N_) {
  int z  = blockIdx.z;
  int o0 = offs[z];
  int ne = offs[z + 1] - o0;

  int flat = blockIdx.y * 32 + blockIdx.x;
  int nid  = (flat & 7) * 64 + (flat >> 3);
  int bm   = nid & 31;
  int bn   = nid >> 5;

  if (bm * 128 >= ne) return;

  const __bf16* Aseg = A  + (size_t)(o0 + bm * 128) * K_;
  const __bf16* Bseg = Bw + ((size_t)z * N_ + bn * 128) * K_;

  __shared__ __align__(16) __bf16 sA0[128 * 64];
  __shared__ __align__(16) __bf16 sB0[128 * 64];
  __shared__ __align__(16) __bf16 sA1[128 * 64];
  __shared__ __align__(16) __bf16 sB1[128 * 64];

  int tid  = threadIdx.x;
  int wave = tid >> 6, lane = tid & 63;
  int wm = wave & 1, wn = wave >> 1;
  int fr = lane & 15;
  int fq = lane >> 4;
  int sw = fr & 7;

  f32x4 acc[4][4];
  #pragma unroll
  for (int i = 0; i < 4; ++i)
    #pragma unroll
    for (int j = 0; j < 4; ++j) acc[i][j] = (f32x4){0.f, 0.f, 0.f, 0.f};

#define STAGE(dA, dB, kbase)                                                  \
  {                                                                           \
    _Pragma("unroll")                                                         \
    for (int it = 0; it < 4; ++it) {                                          \
      int s   = it * 256 + tid;                                               \
      int row = s >> 3;                                                       \
      int cc  = (s & 7) ^ (row & 7);                                          \
      glds16(Aseg + (size_t)row * K_ + (kbase) + cc * 8, &dA[s * 8]);         \
      glds16(Bseg + (size_t)row * K_ + (kbase) + cc * 8, &dB[s * 8]);         \
    }                                                                         \
  }

#define COMPUTE(pA, pB)                                                       \
  {                                                                           \
    const __bf16* rAbase = pA + (wm * 64 + fr) * 64;                          \
    const __bf16* rBbase = pB + (wn * 64 + fr) * 64;                          \
    _Pragma("unroll")                                                         \
    for (int kk = 0; kk < 2; ++kk) {                                          \
      int slot = ((kk * 4 + fq) ^ sw) * 8;                                    \
      bf16x8 af[4], bb[4];                                                    \
      _Pragma("unroll")                                                       \
      for (int i = 0; i < 4; ++i) af[i] = *(const bf16x8*)(rAbase + i * 16 * 64 + slot); \
      _Pragma("unroll")                                                       \
      for (int i = 0; i < 4; ++i) bb[i] = *(const bf16x8*)(rBbase + i * 16 * 64 + slot); \
      _Pragma("unroll")                                                       \
      for (int mi = 0; mi < 4; ++mi)                                          \
        _Pragma("unroll")                                                     \
        for (int ni = 0; ni < 4; ++ni)                                        \
          acc[mi][ni] = __builtin_amdgcn_mfma_f32_16x16x32_bf16(af[mi], bb[ni], acc[mi][ni], 0, 0, 0); \
    }                                                                         \
  }

  STAGE(sA0, sB0, 0)
  asm volatile("s_waitcnt vmcnt(0)" ::: "memory");
  BAR();

  const int nk = K_ >> 6;   // 16 — even
  for (int t = 0; t < nk; t += 2) {
    if (t + 1 < nk) {
      STAGE(sA1, sB1, (t + 1) << 6)
      asm volatile("s_waitcnt vmcnt(8)" ::: "memory");
    } else {
      asm volatile("s_waitcnt vmcnt(0)" ::: "memory");
    }
    BAR();
    COMPUTE(sA0, sB0)
    BAR();
    if (t + 1 < nk) {
      if (t + 2 < nk) {
        STAGE(sA0, sB0, (t + 2) << 6)
        asm volatile("s_waitcnt vmcnt(8)" ::: "memory");
      } else {
        asm volatile("s_waitcnt vmcnt(0)" ::: "memory");
      }
      BAR();
      COMPUTE(sA1, sB1)
      BAR();
    }
  }
#undef STAGE
#undef COMPUTE

  #pragma unroll
  for (int mi = 0; mi < 4; ++mi) {
    #pragma unroll
    for (int r = 0; r < 4; ++r) {
      int rl = bm * 128 + wm * 64 + mi * 16 + fq * 4 + r;
      if (rl < ne) {
        int grow = o0 + rl;
        float* dst = (grow < 8192) ? (c2a + (size_t)grow * 2048)
                                   : (c2b + (size_t)(grow - 8192) * 2048);
        #pragma unroll
        for (int ni = 0; ni < 4; ++ni) {
          int col = bn * 128 + wn * 64 + ni * 16 + fr;
          dst[col] = acc[mi][ni][r];
        }
      }
    }
  }
}

// ---------------- combine: out[t] = c2[r0] + c2[r1] + c2[r2] (fp32, deterministic) ----------------
__global__ void combine_k(const float* __restrict__ c2a, const float* __restrict__ c2b,
                          const int* __restrict__ token_rows, float* __restrict__ out) {
  __shared__ int rr[3];
  int t = blockIdx.x;
  if (threadIdx.x < 3) rr[threadIdx.x] = token_rows[3 * t + threadIdx.x];
  __syncthreads();
  int c = threadIdx.x * 8;
  const float* p0 = c2a + (size_t)rr[0] * 2048 + c;
  const float* p1 = c2a + (size_t)rr[1] * 2048 + c;
  const float* p2 = c2b + (size_t)(rr[2] - 8192) * 2048 + c;
  float4 a0 = *(const float4*)p0,       a1 = *(const float4*)p1,       a2 = *(const float4*)p2;
  float4 b0 = *(const float4*)(p0 + 4), b1 = *(const float4*)(p1 + 4), b2 = *(const float4*)(p2 + 4);
  float4 oa, ob;
  oa.x = a0.x + a1.x + a2.x; oa.y = a0.y + a1.y + a2.y;
  oa.z = a0.z + a1.z + a2.z; oa.w = a0.w + a1.w + a2.w;
  ob.x = b0.x + b1.x + b2.x; ob.y = b0.y + b1.y + b2.y;
  ob.z = b0.z + b1.z + b2.z; ob.w = b0.w + b1.w + b2.w;
  float* op = out + (size_t)t * 2048 + c;
  *(float4*)op = oa;
  *(float4*)(op + 4) = ob;
}

extern "C" void kernel_launch(void* const* d_in, const int* in_sizes, int n_in,
                              void* d_out, int out_size, void* d_ws, size_t ws_size,
                              hipStream_t stream) {
  const float* x   = (const float*)d_in[0];
  const float* gw  = (const float*)d_in[1];
  const float* w1  = (const float*)d_in[2];
  const float* w2  = (const float*)d_in[3];
  const float* w3  = (const float*)d_in[4];
  const float* ws1 = (const float*)d_in[5];
  const float* ws2 = (const float*)d_in[6];
  const float* ws3 = (const float*)d_in[7];
  float* out = (float*)d_out;

  // ---- workspace layout (~190 MB) ----
  char* p = (char*)d_ws;
  int*   counts     = (int*)p;                 // 16 ints
  int*   cursor     = (int*)(p + 64);          // 16 ints
  int*   offs       = (int*)(p + 128);         // 10 ints
  int*   done       = (int*)(p + 192);         // 1 int (router completion counter)
  int*   sel        = (int*)(p + 1024);        // 8192 ints
  float* sco        = (float*)(p + 1024 + 32768);
  int*   token_rows = (int*)(p + 1024 + 65536); // 12288 ints
  char* big = p + (1 << 20);
  __bf16* w13  = (__bf16*)big;                                              // 75,497,472 B
  __bf16* w2c  = (__bf16*)(big + 75497472ull);                              // 37,748,736 B
  __bf16* xg   = (__bf16*)(big + 75497472ull + 37748736ull);                // 50,331,648 B
  __bf16* hbuf = (__bf16*)(big + 75497472ull + 37748736ull + 50331648ull);  // 25,165,824 B
  float*  c2a  = (float*)w13;   // overlay: w13 dead after GEMM1 (8192*2048*4 = 67.1 MB <= 75.5 MB)
  float*  c2b  = (float*)xg;    // overlay: xg dead after GEMM1 (4096*2048*4 = 33.5 MB <= 50.3 MB)

  hipMemsetAsync(p, 0, 256, stream);  // counts + cursors + offs + done

  convert_w<<<27648, 256, 0, stream>>>(w1, w2, w3, ws1, ws2, ws3, w13, w2c);
  router_k<<<TTOK / 4, 256, 0, stream>>>(x, gw, sel, sco, counts, done, offs);
  gather_k<<<TTOK, 256, 0, stream>>>(x, sel, sco, offs, cursor, token_rows, xg);
  gemm_wide<<<dim3(32, 16, 9), 128, 0, stream>>>(xg, w13, hbuf, offs, 2048, 2048);
  gemm_nt2<<<dim3(32, 16, 9), 256, 0, stream>>>(hbuf, w2c, c2a, c2b, offs, 1024, 2048);
  combine_k<<<TTOK, 256, 0, stream>>>(c2a, c2b, token_rows, out);
}

// Round 7
// 717.302 us; speedup vs baseline: 1.1486x; 1.1486x over previous
//
#include <hip/hip_runtime.h>
#include <hip/hip_bf16.h>
#include <cstdint>

// ---- problem constants (bs=4, slen=1024 -> T=4096; dim=2048; hidden=1024; E=8; top-2) ----
#define TTOK   4096
#define DIM    2048
#define HID    1024
#define NEXP   8          // routed experts
#define GROWS  12288      // TTOK*2 routed rows + TTOK shared rows

typedef __attribute__((ext_vector_type(8))) __bf16 bf16x8;
typedef __attribute__((ext_vector_type(4))) float  f32x4;

__device__ __forceinline__ void glds16(const void* g, void* l) {
  __builtin_amdgcn_global_load_lds((const __attribute__((address_space(1))) void*)g,
                                   (__attribute__((address_space(3))) void*)l,
                                   16, 0, 0);
}

// raw barrier (no compiler-inserted vmcnt(0) drain); memory clobbers pin LDS/glds ordering
#define BAR() do { asm volatile("" ::: "memory"); __builtin_amdgcn_s_barrier(); \
                   asm volatile("" ::: "memory"); } while (0)

// ---------------- merged weight-convert + router (independent work, one dispatch) ----------------
// Convert part (blocks [0, 27648)):
//   w13cat (9 x 2048 x 2048): rows INTERLEAVED per expert: new_r = 2j -> w1[j], 2j+1 -> w3[j],
//   so GEMM1 output col pairs (2j,2j+1) = (h1_j,h3_j) -> silu fused in GEMM1 epilogue via shfl_xor(1).
//   w2cat (9 x 2048 x 1024) plain bf16 cast.
// Router part (blocks [27648, 28672)): one wave per token, fp32 logits, sigmoid, top-2.
__global__ void convert_router_k(const float* __restrict__ w1, const float* __restrict__ w2,
                                 const float* __restrict__ w3, const float* __restrict__ ws1,
                                 const float* __restrict__ ws2, const float* __restrict__ ws3,
                                 __bf16* __restrict__ w13, __bf16* __restrict__ w2c,
                                 const float* __restrict__ x, const float* __restrict__ gw,
                                 int* __restrict__ sel, float* __restrict__ sco,
                                 int* __restrict__ counts) {
  const int N1 = 9 * 2048 * 2048 / 8;   // 16B-out chunks for w13
  const int N2 = 9 * 2048 * 1024 / 8;   // chunks for w2c
  const int CONV_BLOCKS = (N1 + N2) / 256;  // 27648

  if (blockIdx.x < (unsigned)CONV_BLOCKS) {
    int s = blockIdx.x * 256 + threadIdx.x;
    const float* src;
    __bf16* dst;
    if (s < N1) {
      int e  = s / 524288;            // 2048*2048/8
      int r  = (s % 524288) / 256;    // source row 0..2047
      int c  = (s % 256) * 8;
      int nr;
      if (r < 1024) { src = (e < 8 ? w1 + ((size_t)e * 1024 + r) * 2048 : ws1 + (size_t)r * 2048) + c;
                      nr = 2 * r; }
      else          { src = (e < 8 ? w3 + ((size_t)e * 1024 + (r - 1024)) * 2048 : ws3 + (size_t)(r - 1024) * 2048) + c;
                      nr = 2 * (r - 1024) + 1; }
      dst = w13 + ((size_t)e * 2048 + nr) * 2048 + c;
    } else {
      int s2 = s - N1;
      int e  = s2 / 262144;           // 2048*1024/8
      int r  = (s2 % 262144) / 128;   // row (d) 0..2047
      int c  = (s2 % 128) * 8;
      src = (e < 8 ? w2 + ((size_t)e * 2048 + r) * 1024 : ws2 + (size_t)r * 1024) + c;
      dst = w2c + ((size_t)e * 2048 + r) * 1024 + c;
    }
    float4 a = *(const float4*)(src);
    float4 b = *(const float4*)(src + 4);
    bf16x8 o;
    o[0]=(__bf16)a.x; o[1]=(__bf16)a.y; o[2]=(__bf16)a.z; o[3]=(__bf16)a.w;
    o[4]=(__bf16)b.x; o[5]=(__bf16)b.y; o[6]=(__bf16)b.z; o[7]=(__bf16)b.w;
    *(bf16x8*)dst = o;
    return;
  }

  // ---- router path ----
  int t    = (blockIdx.x - CONV_BLOCKS) * 4 + (threadIdx.x >> 6);
  int lane = threadIdx.x & 63;
  const float* xr = x + (size_t)t * DIM;
  float acc[NEXP];
  #pragma unroll
  for (int e = 0; e < NEXP; ++e) acc[e] = 0.f;
  for (int d = lane * 4; d < DIM; d += 256) {
    float4 xv = *(const float4*)(xr + d);
    #pragma unroll
    for (int e = 0; e < NEXP; ++e) {
      float4 gv = *(const float4*)(gw + (size_t)e * DIM + d);
      acc[e] += xv.x * gv.x + xv.y * gv.y + xv.z * gv.z + xv.w * gv.w;
    }
  }
  #pragma unroll
  for (int off = 32; off; off >>= 1)
    #pragma unroll
    for (int e = 0; e < NEXP; ++e) acc[e] += __shfl_xor(acc[e], off);
  if (lane == 0) {
    float s[NEXP];
    #pragma unroll
    for (int e = 0; e < NEXP; ++e) s[e] = 1.f / (1.f + expf(-acc[e]));
    int e0 = 0;
    #pragma unroll
    for (int e = 1; e < NEXP; ++e) if (s[e] > s[e0]) e0 = e;
    int e1 = (e0 == 0) ? 1 : 0;
    #pragma unroll
    for (int e = 0; e < NEXP; ++e) if (e != e0 && s[e] > s[e1]) e1 = e;
    sel[2 * t] = e0; sel[2 * t + 1] = e1;
    sco[2 * t] = s[e0]; sco[2 * t + 1] = s[e1];
    atomicAdd(&counts[e0], 1); atomicAdd(&counts[e1], 1);
  }
}

// ---------------- exclusive scan over 9 segments (expert 8 = shared, count TTOK) ----------------
__global__ void scan_k(const int* __restrict__ counts, int* __restrict__ offs) {
  if (threadIdx.x == 0 && blockIdx.x == 0) {
    int o = 0;
    for (int e = 0; e < NEXP; ++e) { offs[e] = o; o += counts[e]; }
    offs[NEXP] = o;            // == 8192
    offs[NEXP + 1] = o + TTOK; // == 12288
  }
}

// ---------------- gather: write score-scaled bf16 rows into compact segments ----------------
__global__ void gather_k(const float* __restrict__ x, const int* __restrict__ sel,
                         const float* __restrict__ sco, const int* __restrict__ offs,
                         int* __restrict__ cursor, int* __restrict__ token_rows,
                         __bf16* __restrict__ xg) {
  __shared__ int   rows[3];
  __shared__ float ss[3];
  int t = blockIdx.x;
  if (threadIdx.x == 0) {
    int e0 = sel[2 * t], e1 = sel[2 * t + 1];
    int r0 = offs[e0] + atomicAdd(&cursor[e0], 1);
    int r1 = offs[e1] + atomicAdd(&cursor[e1], 1);
    int r2 = 8192 + t; // shared segment starts at 8192 always
    rows[0] = r0; rows[1] = r1; rows[2] = r2;
    ss[0] = sco[2 * t]; ss[1] = sco[2 * t + 1]; ss[2] = 1.0f;
    token_rows[3 * t] = r0; token_rows[3 * t + 1] = r1; token_rows[3 * t + 2] = r2;
  }
  __syncthreads();
  int c = threadIdx.x * 8;
  float4 v0 = *(const float4*)(x + (size_t)t * DIM + c);
  float4 v1 = *(const float4*)(x + (size_t)t * DIM + c + 4);
  #pragma unroll
  for (int j = 0; j < 3; ++j) {
    float s = ss[j];
    bf16x8 o;
    o[0]=(__bf16)(v0.x*s); o[1]=(__bf16)(v0.y*s); o[2]=(__bf16)(v0.z*s); o[3]=(__bf16)(v0.w*s);
    o[4]=(__bf16)(v1.x*s); o[5]=(__bf16)(v1.y*s); o[6]=(__bf16)(v1.z*s); o[7]=(__bf16)(v1.w*s);
    *(bf16x8*)(xg + (size_t)rows[j] * DIM + c) = o;
  }
}

// ---------------- grouped NT GEMM, 128x128 tile, BK=64 (R4 core + 4x4 SUPER-TILE XCD swizzle) ----------------
// SINGLE CHANGE vs R4 (A/B isolation): block->tile mapping. Old chunking gave each XCD
// 32bm x 2bn (16 MB A-stream >> 4 MB L2 -> staged A loads are HBM misses, ~900cy; FETCH 316MB
// = 2.5x unique). New: each XCD works a 4bm x 4bn SUPER-TILE (4 A-tiles + 4 B-panels = 4 MB,
// L2-fit), bijective, balanced for small-ne segments (ne~1024 -> every XCD gets exactly one
// valid super-tile). Mechanism: 2-phase structure's cost IS exposed stage latency (m233);
// L2-hit staging (~200cy) shortens the drain directly.
// Pipeline per K-step (R4, proven): issue next tile's 8 glds -> vmcnt(8) -> s_barrier ->
// compute -> s_barrier.  LDS: chunk j (16B) of tile-row r at slot j^(r&7); staging permutes
// the GLOBAL chunk per lane (glds16 LDS dest fixed - m104). 0 bank conflicts measured.
// EPI=0: fused silu(h1)*h3 epilogue (w13 rows interleaved), writes bf16 h (GROWS x 1024).
// EPI=1: fp32 stores into split c2 buffers (no atomics).
template <int EPI>
__launch_bounds__(256)
__global__ void gemm_nt(const __bf16* __restrict__ A, const __bf16* __restrict__ Bw,
                        __bf16* __restrict__ Hb, float* __restrict__ c2a, float* __restrict__ c2b,
                        const int* __restrict__ offs, int K_, int N_) {
  int z  = blockIdx.z;
  int o0 = offs[z];
  int ne = offs[z + 1] - o0;

  // 4x4 super-tile XCD swizzle (bijective over 512 blocks):
  // xcd = flat&7 (dispatch round-robins XCDs); its 64 blocks = 4 super-tiles of 16.
  // bm = ((xcd>>2) + 2*s)*4 + (pos&3), bn = (xcd&3)*4 + (pos>>2).
  int flat = blockIdx.y * 32 + blockIdx.x;  // 0..511, ascending dispatch order
  int xcd  = flat & 7;
  int r    = flat >> 3;                     // 0..63 within XCD
  int s    = r >> 4;                        // super-tile 0..3
  int pos  = r & 15;                        // position in 4x4 super-tile
  int bm   = ((xcd >> 2) + 2 * s) * 4 + (pos & 3);
  int bn   = (xcd & 3) * 4 + (pos >> 2);

  if (bm * 128 >= ne) return;

  const __bf16* Aseg = A  + (size_t)(o0 + bm * 128) * K_;
  const __bf16* Bseg = Bw + ((size_t)z * N_ + bn * 128) * K_;

  __shared__ __align__(16) __bf16 sA[2][128 * 64];
  __shared__ __align__(16) __bf16 sB[2][128 * 64];

  int tid  = threadIdx.x;
  int wave = tid >> 6, lane = tid & 63;
  int wm = wave & 1, wn = wave >> 1;
  int fr = lane & 15;   // fragment row (m for A, n for B, also out col)
  int fq = lane >> 4;   // quad
  int sw = fr & 7;      // lane-constant XOR swizzle (16 | row strides)

  f32x4 acc[4][4];
  #pragma unroll
  for (int i = 0; i < 4; ++i)
    #pragma unroll
    for (int j = 0; j < 4; ++j) acc[i][j] = (f32x4){0.f, 0.f, 0.f, 0.f};

#define STAGE(buf, kbase)                                                     \
  {                                                                           \
    _Pragma("unroll")                                                         \
    for (int it = 0; it < 4; ++it) {                                          \
      int ss_ = it * 256 + tid;                                               \
      int row = ss_ >> 3;                                                     \
      int c8  = (ss_ & 7) ^ (row & 7);                                        \
      glds16(Aseg + (size_t)row * K_ + (kbase) + c8 * 8, &sA[buf][ss_ * 8]);  \
      glds16(Bseg + (size_t)row * K_ + (kbase) + c8 * 8, &sB[buf][ss_ * 8]);  \
    }                                                                         \
  }

  // prologue: stage tile 0 into buf 0, full drain once
  STAGE(0, 0)
  asm volatile("s_waitcnt vmcnt(0)" ::: "memory");
  BAR();

  const int nk = K_ >> 6;
  for (int t = 0; t < nk; ++t) {
    int cur = t & 1;
    if (t + 1 < nk) {
      STAGE(cur ^ 1, (t + 1) << 6)                       // 8 loads fly across this K-step
      asm volatile("s_waitcnt vmcnt(8)" ::: "memory");   // previous tile's 8 landed (own)
    } else {
      asm volatile("s_waitcnt vmcnt(0)" ::: "memory");
    }
    BAR();                                               // all waves: buf[cur] fully landed

    const __bf16* rAbase = &sA[cur][(wm * 64 + fr) * 64];
    const __bf16* rBbase = &sB[cur][(wn * 64 + fr) * 64];
    #pragma unroll
    for (int kk = 0; kk < 2; ++kk) {
      int slot = ((kk * 4 + fq) ^ sw) * 8;
      bf16x8 af[4], bb[4];
      #pragma unroll
      for (int i = 0; i < 4; ++i) af[i] = *(const bf16x8*)(rAbase + i * 16 * 64 + slot);
      #pragma unroll
      for (int i = 0; i < 4; ++i) bb[i] = *(const bf16x8*)(rBbase + i * 16 * 64 + slot);
      #pragma unroll
      for (int mi = 0; mi < 4; ++mi)
        #pragma unroll
        for (int ni = 0; ni < 4; ++ni)
          acc[mi][ni] = __builtin_amdgcn_mfma_f32_16x16x32_bf16(af[mi], bb[ni], acc[mi][ni], 0, 0, 0);
    }
    BAR();                                               // reads of buf[cur] done before overwrite
  }
#undef STAGE

  // epilogue: C/D layout col = lane&15 (=fr), row = fq*4 + r   [m89/m91 verified]
  #pragma unroll
  for (int mi = 0; mi < 4; ++mi) {
    #pragma unroll
    for (int rr = 0; rr < 4; ++rr) {
      int rl = bm * 128 + wm * 64 + mi * 16 + fq * 4 + rr;
      bool ok = rl < ne;
      int grow = o0 + rl;
      if (EPI == 0) {
        // fused silu: col pairs (2j,2j+1) = (h1_j, h3_j); lane parity == col parity
        #pragma unroll
        for (int ni = 0; ni < 4; ++ni) {
          float v = acc[mi][ni][rr];
          float o = __shfl_xor(v, 1);          // partner holds the other half of (h1,h3) pair
          float h1 = (fr & 1) ? o : v;
          float h3 = (fr & 1) ? v : o;
          float g  = h1 / (1.f + expf(-h1)) * h3;
          if (ok && !(fr & 1)) {
            int hcol = bn * 64 + wn * 32 + ni * 8 + (fr >> 1);
            Hb[(size_t)grow * 1024 + hcol] = (__bf16)g;
          }
        }
      } else {
        if (ok) {
          float* dst = (grow < 8192) ? (c2a + (size_t)grow * 2048)
                                     : (c2b + (size_t)(grow - 8192) * 2048);
          #pragma unroll
          for (int ni = 0; ni < 4; ++ni) {
            int col = bn * 128 + wn * 64 + ni * 16 + fr;
            dst[col] = acc[mi][ni][rr];
          }
        }
      }
    }
  }
}

// ---------------- combine: out[t] = c2[r0] + c2[r1] + c2[r2] (fp32, deterministic) ----------------
__global__ void combine_k(const float* __restrict__ c2a, const float* __restrict__ c2b,
                          const int* __restrict__ token_rows, float* __restrict__ out) {
  __shared__ int rr[3];
  int t = blockIdx.x;
  if (threadIdx.x < 3) rr[threadIdx.x] = token_rows[3 * t + threadIdx.x];
  __syncthreads();
  int c = threadIdx.x * 8;
  const float* p0 = c2a + (size_t)rr[0] * 2048 + c;
  const float* p1 = c2a + (size_t)rr[1] * 2048 + c;
  const float* p2 = c2b + (size_t)(rr[2] - 8192) * 2048 + c;
  float4 a0 = *(const float4*)p0,       a1 = *(const float4*)p1,       a2 = *(const float4*)p2;
  float4 b0 = *(const float4*)(p0 + 4), b1 = *(const float4*)(p1 + 4), b2 = *(const float4*)(p2 + 4);
  float4 oa, ob;
  oa.x = a0.x + a1.x + a2.x; oa.y = a0.y + a1.y + a2.y;
  oa.z = a0.z + a1.z + a2.z; oa.w = a0.w + a1.w + a2.w;
  ob.x = b0.x + b1.x + b2.x; ob.y = b0.y + b1.y + b2.y;
  ob.z = b0.z + b1.z + b2.z; ob.w = b0.w + b1.w + b2.w;
  float* op = out + (size_t)t * 2048 + c;
  *(float4*)op = oa;
  *(float4*)(op + 4) = ob;
}

extern "C" void kernel_launch(void* const* d_in, const int* in_sizes, int n_in,
                              void* d_out, int out_size, void* d_ws, size_t ws_size,
                              hipStream_t stream) {
  const float* x   = (const float*)d_in[0];
  const float* gw  = (const float*)d_in[1];
  const float* w1  = (const float*)d_in[2];
  const float* w2  = (const float*)d_in[3];
  const float* w3  = (const float*)d_in[4];
  const float* ws1 = (const float*)d_in[5];
  const float* ws2 = (const float*)d_in[6];
  const float* ws3 = (const float*)d_in[7];
  float* out = (float*)d_out;

  // ---- workspace layout (~190 MB) ----
  char* p = (char*)d_ws;
  int*   counts     = (int*)p;                 // 16 ints
  int*   cursor     = (int*)(p + 64);          // 16 ints
  int*   offs       = (int*)(p + 128);         // 10 ints
  int*   sel        = (int*)(p + 1024);        // 8192 ints
  float* sco        = (float*)(p + 1024 + 32768);
  int*   token_rows = (int*)(p + 1024 + 65536); // 12288 ints
  char* big = p + (1 << 20);
  __bf16* w13  = (__bf16*)big;                                              // 75,497,472 B
  __bf16* w2c  = (__bf16*)(big + 75497472ull);                              // 37,748,736 B
  __bf16* xg   = (__bf16*)(big + 75497472ull + 37748736ull);                // 50,331,648 B
  __bf16* hbuf = (__bf16*)(big + 75497472ull + 37748736ull + 50331648ull);  // 25,165,824 B
  float*  c2a  = (float*)w13;   // overlay: w13 dead after GEMM1 (8192*2048*4 = 67.1 MB <= 75.5 MB)
  float*  c2b  = (float*)xg;    // overlay: xg dead after GEMM1 (4096*2048*4 = 33.5 MB <= 50.3 MB)

  hipMemsetAsync(p, 0, 256, stream);  // counts + cursors

  convert_router_k<<<27648 + TTOK / 4, 256, 0, stream>>>(w1, w2, w3, ws1, ws2, ws3, w13, w2c,
                                                         x, gw, sel, sco, counts);
  scan_k<<<1, 64, 0, stream>>>(counts, offs);
  gather_k<<<TTOK, 256, 0, stream>>>(x, sel, sco, offs, cursor, token_rows, xg);
  gemm_nt<0><<<dim3(32, 16, 9), 256, 0, stream>>>(xg, w13, hbuf, nullptr, nullptr, offs, 2048, 2048);
  gemm_nt<1><<<dim3(32, 16, 9), 256, 0, stream>>>(hbuf, w2c, nullptr, c2a, c2b, offs, 1024, 2048);
  combine_k<<<TTOK, 256, 0, stream>>>(c2a, c2b, token_rows, out);
}